// Round 3
// baseline (229.861 us; speedup 1.0000x reference)
//
#include <hip/hip_runtime.h>
#include <hip/hip_bf16.h>

#define B_ 2
#define S_ 2048
#define D_ 1024
#define H_ 16
#define DH 64
#define M_ (B_*S_)   // 4096
#define NT_ (S_/64)  // 32 q tiles per (b,h)
#define KVB 128      // kv rounds of 128

using bf16x8 = __attribute__((ext_vector_type(8))) __bf16;
using f32x4  = __attribute__((ext_vector_type(4))) float;

// swizzle key: varies with row bits 0..2 AND 3..5 (element units, flips the
// 16B-block index within a 64-elem group)
__device__ __forceinline__ int swz(int row) { return ((row ^ (row >> 3)) & 7) << 3; }

__device__ __forceinline__ void glds16(const __bf16* g, __bf16* l) {
#if __has_builtin(__builtin_amdgcn_global_load_lds)
  __builtin_amdgcn_global_load_lds(
      (const __attribute__((address_space(1))) unsigned int*)g,
      (__attribute__((address_space(3))) unsigned int*)l, 16, 0, 0);
#else
  *(bf16x8*)l = *(const bf16x8*)g;
#endif
}

// ---------- convert x fp32 -> bf16, pre-swizzled within 64-col k-groups ----
__global__ __launch_bounds__(256) void conv_x(const float* __restrict__ x,
                                              __bf16* __restrict__ xb) {
  int idx = blockIdx.x * 256 + threadIdx.x;
  int m = idx >> 7, k = (idx & 127) * 8;
  float4 a = *(const float4*)&x[(size_t)m * D_ + k];
  float4 b = *(const float4*)&x[(size_t)m * D_ + k + 4];
  bf16x8 o;
  o[0]=(__bf16)a.x; o[1]=(__bf16)a.y; o[2]=(__bf16)a.z; o[3]=(__bf16)a.w;
  o[4]=(__bf16)b.x; o[5]=(__bf16)b.y; o[6]=(__bf16)b.z; o[7]=(__bf16)b.w;
  *(bf16x8*)&xb[(size_t)m * D_ + (k & ~63) + ((k & 63) ^ swz(m))] = o;
}

// ---------- transpose+convert W [k][n] fp32 -> Wt [n][k] bf16 (pre-swz) ----
__global__ __launch_bounds__(256) void conv_w(const float* __restrict__ Wq,
                                              const float* __restrict__ Wk,
                                              const float* __restrict__ Wv,
                                              __bf16* __restrict__ wt) {
  int z = blockIdx.z;
  const float* __restrict__ W = (z == 0) ? Wq : (z == 1) ? Wk : Wv;
  __bf16* __restrict__ Wt = wt + (size_t)z * D_ * D_;
  __shared__ __bf16 Lt[64 * 66];
  int tid = threadIdx.x;
  int k0 = blockIdx.x * 64, n0 = blockIdx.y * 64;
  #pragma unroll
  for (int i = 0; i < 4; ++i) {
    int f4 = i * 256 + tid;
    int r = f4 >> 4, c4 = (f4 & 15) * 4;
    float4 v = *(const float4*)&W[(size_t)(k0 + r) * D_ + n0 + c4];
    Lt[(c4 + 0) * 66 + r] = (__bf16)v.x;
    Lt[(c4 + 1) * 66 + r] = (__bf16)v.y;
    Lt[(c4 + 2) * 66 + r] = (__bf16)v.z;
    Lt[(c4 + 3) * 66 + r] = (__bf16)v.w;
  }
  __syncthreads();
  #pragma unroll
  for (int i = 0; i < 2; ++i) {
    int idx = i * 256 + tid;
    int n = idx >> 3, kc = (idx & 7) * 8;
    int nf = n0 + n;
    bf16x8 o;
    #pragma unroll
    for (int j = 0; j < 8; ++j) o[j] = Lt[n * 66 + kc + j];
    *(bf16x8*)&Wt[(size_t)nf * D_ + k0 + (kc ^ swz(nf))] = o;
  }
}

// ---------- QKV GEMM, m97-style (no setprio) -------------------------------
__global__ __launch_bounds__(256) void qkv_gemm(
    const __bf16* __restrict__ xb, const __bf16* __restrict__ wt,
    const float* __restrict__ bq, const float* __restrict__ bk,
    const float* __restrict__ bv, __bf16* __restrict__ qkv) {
  int z = blockIdx.z;
  const __bf16* __restrict__ Wt = wt + (size_t)z * D_ * D_;
  const float* __restrict__ bias = (z == 0) ? bq : (z == 1) ? bk : bv;
  __bf16* __restrict__ out = qkv + (size_t)z * M_ * D_;
  const float scale = (z == 0) ? 0.125f : 1.0f;

  __shared__ __bf16 Al[128 * 64];
  __shared__ __bf16 Bl[128 * 64];

  int tid = threadIdx.x, lane = tid & 63, w = tid >> 6;
  int m0 = blockIdx.y * 128, n0 = blockIdx.x * 128;
  int wr = (w >> 1) * 64, wc = (w & 1) * 64;

  f32x4 acc[4][4] = {};

  for (int kt = 0; kt < D_ / 64; ++kt) {
    int k0 = kt * 64;
    #pragma unroll
    for (int r = 0; r < 4; ++r) {
      int e = (r * 256 + tid) * 8;
      int row = e >> 6, col = e & 63;
      glds16(&xb[(size_t)(m0 + row) * D_ + k0 + col], &Al[e]);
      glds16(&Wt[(size_t)(n0 + row) * D_ + k0 + col], &Bl[e]);
    }
    __syncthreads();

    bf16x8 af[4][2], bfr[4][2];
    #pragma unroll
    for (int mi = 0; mi < 4; ++mi) {
      int row = wr + mi * 16 + (lane & 15);
      int sr = swz(row);
      #pragma unroll
      for (int kk = 0; kk < 2; ++kk)
        af[mi][kk] = *(const bf16x8*)&Al[row * 64 + ((kk * 32 + (lane >> 4) * 8) ^ sr)];
    }
    #pragma unroll
    for (int ni = 0; ni < 4; ++ni) {
      int col = wc + ni * 16 + (lane & 15);
      int sc = swz(col);
      #pragma unroll
      for (int kk = 0; kk < 2; ++kk)
        bfr[ni][kk] = *(const bf16x8*)&Bl[col * 64 + ((kk * 32 + (lane >> 4) * 8) ^ sc)];
    }
    #pragma unroll
    for (int kk = 0; kk < 2; ++kk)
      #pragma unroll
      for (int mi = 0; mi < 4; ++mi)
        #pragma unroll
        for (int ni = 0; ni < 4; ++ni)
          acc[mi][ni] = __builtin_amdgcn_mfma_f32_16x16x32_bf16(
              af[mi][kk], bfr[ni][kk], acc[mi][ni], 0, 0, 0);
    __syncthreads();
  }

  #pragma unroll
  for (int mi = 0; mi < 4; ++mi) {
    #pragma unroll
    for (int ni = 0; ni < 4; ++ni) {
      int col = n0 + wc + ni * 16 + (lane & 15);
      int h = col >> 6, dh = col & 63;
      float bv_ = bias[col];
      #pragma unroll
      for (int r = 0; r < 4; ++r) {
        int row = m0 + wr + mi * 16 + (lane >> 4) * 4 + r;
        int b = row >> 11, s = row & 2047;
        out[((size_t)(b * H_ + h) * S_ + s) * DH + dh] =
            (__bf16)((acc[mi][ni][r] + bv_) * scale);
      }
    }
  }
}

// ---------- flash attention: KVB=128 rounds, reg-prefetch staging ----------
__device__ __forceinline__ void attn_tile8(
    const bf16x8* aq, f32x4* accO, float* mrow, float* lrow,
    const __bf16* __restrict__ Kl, const __bf16* __restrict__ Vt,
    __bf16* __restrict__ Plw, int lane, int kv0, int qbase, bool diag) {
  f32x4 sf[8];
  __builtin_amdgcn_s_setprio(1);
  #pragma unroll
  for (int f = 0; f < 8; ++f) {
    f32x4 zz = {};
    int col = f * 16 + (lane & 15);
    int sc = swz(col);
    #pragma unroll
    for (int kk = 0; kk < 2; ++kk) {
      bf16x8 bk = *(const bf16x8*)&Kl[col * 64 + ((kk * 32 + (lane >> 4) * 8) ^ sc)];
      zz = __builtin_amdgcn_mfma_f32_16x16x32_bf16(aq[kk], bk, zz, 0, 0, 0);
    }
    sf[f] = zz;
  }
  __builtin_amdgcn_s_setprio(0);

  if (diag) {
    #pragma unroll
    for (int f = 0; f < 8; ++f) {
      int kvg = kv0 + f * 16 + (lane & 15);
      #pragma unroll
      for (int r = 0; r < 4; ++r) {
        int qg = qbase + (lane >> 4) * 4 + r;
        if (kvg > qg) sf[f][r] = -1e30f;
      }
    }
  }

  float alpha[4];
  #pragma unroll
  for (int r = 0; r < 4; ++r) {
    float mx = sf[0][r];
    #pragma unroll
    for (int f = 1; f < 8; ++f) mx = fmaxf(mx, sf[f][r]);
    #pragma unroll
    for (int off = 8; off >= 1; off >>= 1)
      mx = fmaxf(mx, __shfl_xor(mx, off, 64));
    float mnew = fmaxf(mrow[r], mx);
    alpha[r] = __expf(mrow[r] - mnew);
    mrow[r] = mnew;
    float rs = 0.f;
    #pragma unroll
    for (int f = 0; f < 8; ++f) {
      float p = __expf(sf[f][r] - mnew);
      sf[f][r] = p;
      rs += p;
    }
    #pragma unroll
    for (int off = 8; off >= 1; off >>= 1)
      rs += __shfl_xor(rs, off, 64);
    lrow[r] = lrow[r] * alpha[r] + rs;
  }

  #pragma unroll
  for (int f = 0; f < 8; ++f)
    #pragma unroll
    for (int r = 0; r < 4; ++r) {
      int row = (lane >> 4) * 4 + r;
      Plw[row * KVB + ((f * 16 + (lane & 15)) ^ swz(row))] = (__bf16)sf[f][r];
    }

  #pragma unroll
  for (int f = 0; f < 4; ++f)
    #pragma unroll
    for (int r = 0; r < 4; ++r)
      accO[f][r] *= alpha[r];

  __builtin_amdgcn_s_setprio(1);
  #pragma unroll
  for (int kk = 0; kk < 4; ++kk) {
    int prow = lane & 15;
    bf16x8 pa = *(const bf16x8*)&Plw[prow * KVB + ((kk * 32 + (lane >> 4) * 8) ^ swz(prow))];
    #pragma unroll
    for (int f = 0; f < 4; ++f) {
      int vrow = f * 16 + (lane & 15);
      bf16x8 vb = *(const bf16x8*)&Vt[vrow * KVB + ((kk * 32 + (lane >> 4) * 8) ^ swz(vrow))];
      accO[f] = __builtin_amdgcn_mfma_f32_16x16x32_bf16(pa, vb, accO[f], 0, 0, 0);
    }
  }
  __builtin_amdgcn_s_setprio(0);
}

__device__ __forceinline__ void attn_out(
    const f32x4* accO, const float* lrow, float* __restrict__ out,
    int b, int h, int qbase, int lane) {
  #pragma unroll
  for (int f = 0; f < 4; ++f) {
    int dh = f * 16 + (lane & 15);
    #pragma unroll
    for (int r = 0; r < 4; ++r) {
      int qg = qbase + (lane >> 4) * 4 + r;
      out[((size_t)(b * S_ + qg)) * D_ + h * DH + dh] = accO[f][r] / lrow[r];
    }
  }
}

__global__ __launch_bounds__(256) void attn(
    const __bf16* __restrict__ Q, const __bf16* __restrict__ K,
    const __bf16* __restrict__ V, float* __restrict__ out) {
  __shared__ __bf16 Kl[KVB * 64];     // [kv][dh], swizzled
  __shared__ __bf16 Vt[64 * KVB];     // [dh][kv], swizzled
  __shared__ __bf16 Pl[4][16 * KVB];  // per-wave P

  int tid = threadIdx.x, lane = tid & 63, w = tid >> 6;
  int bx = blockIdx.x, h = blockIdx.y, b = blockIdx.z;
  int qA0 = bx * 64, qB0 = (NT_ - 1 - bx) * 64;
  size_t base = ((size_t)(b * H_ + h)) * S_ * DH;
  const __bf16* __restrict__ Qg = Q + base;
  const __bf16* __restrict__ Kg = K + base;
  const __bf16* __restrict__ Vg = V + base;

  bf16x8 aqA[2], aqB[2];
  int qra = qA0 + w * 16 + (lane & 15), qrb = qB0 + w * 16 + (lane & 15);
  #pragma unroll
  for (int kk = 0; kk < 2; ++kk) {
    aqA[kk] = *(const bf16x8*)&Qg[(size_t)qra * DH + kk * 32 + (lane >> 4) * 8];
    aqB[kk] = *(const bf16x8*)&Qg[(size_t)qrb * DH + kk * 32 + (lane >> 4) * 8];
  }

  f32x4 accA[4] = {}, accB[4] = {};
  float mA[4], lA[4], mB[4], lB[4];
  #pragma unroll
  for (int r = 0; r < 4; ++r) { mA[r] = mB[r] = -1e30f; lA[r] = lB[r] = 0.f; }

  const int ktAmax = (qA0 + 63) >> 7;   // last 128-round tile A needs
  const int ktBmax = (qB0 + 63) >> 7;   // >= 8 > ktAmax always

  // prologue: load round 0 into staging regs
  bf16x8 kreg[4], vreg[4];
  #pragma unroll
  for (int i = 0; i < 4; ++i) {
    int e = (i * 256 + tid) * 8;
    int kv = e >> 6, d0 = e & 63;
    kreg[i] = *(const bf16x8*)&Kg[(size_t)kv * DH + d0];
    vreg[i] = *(const bf16x8*)&Vg[(size_t)kv * DH + d0];
  }

  for (int kt = 0; kt <= ktBmax; ++kt) {
    int kv0 = kt * KVB;
    // write staged regs -> LDS (K vectorized, V transposed scalar)
    #pragma unroll
    for (int i = 0; i < 4; ++i) {
      int e = (i * 256 + tid) * 8;
      int kv = e >> 6, d0 = e & 63;
      *(bf16x8*)&Kl[kv * 64 + (d0 ^ swz(kv))] = kreg[i];
      #pragma unroll
      for (int j = 0; j < 8; ++j) {
        int row = d0 + j;
        Vt[row * KVB + (kv ^ swz(row))] = vreg[i][j];
      }
    }
    __syncthreads();

    // issue next round's loads; they fly under the compute below
    if (kt < ktBmax) {
      int kvn = kv0 + KVB;
      #pragma unroll
      for (int i = 0; i < 4; ++i) {
        int e = (i * 256 + tid) * 8;
        int kv = e >> 6, d0 = e & 63;
        kreg[i] = *(const bf16x8*)&Kg[(size_t)(kvn + kv) * DH + d0];
        vreg[i] = *(const bf16x8*)&Vg[(size_t)(kvn + kv) * DH + d0];
      }
    }

    attn_tile8(aqB, accB, mB, lB, Kl, Vt, Pl[w], lane, kv0, qB0 + w * 16,
               kv0 + KVB - 1 > qB0);
    if (kt <= ktAmax)
      attn_tile8(aqA, accA, mA, lA, Kl, Vt, Pl[w], lane, kv0, qA0 + w * 16,
                 kv0 + KVB - 1 > qA0);
    __syncthreads();
  }

  attn_out(accA, lA, out, b, h, qA0 + w * 16, lane);
  attn_out(accB, lB, out, b, h, qB0 + w * 16, lane);
}

extern "C" void kernel_launch(void* const* d_in, const int* in_sizes, int n_in,
                              void* d_out, int out_size, void* d_ws, size_t ws_size,
                              hipStream_t stream) {
  const float* x  = (const float*)d_in[0];
  const float* Wq = (const float*)d_in[1];
  const float* bq = (const float*)d_in[2];
  const float* Wk = (const float*)d_in[3];
  const float* bk = (const float*)d_in[4];
  const float* Wv = (const float*)d_in[5];
  const float* bv = (const float*)d_in[6];
  float* out = (float*)d_out;

  __bf16* xb  = (__bf16*)d_ws;             // 8 MB
  __bf16* wt  = xb + (size_t)M_ * D_;      // 6 MB
  __bf16* qkv = wt + (size_t)3 * D_ * D_;  // 24 MB
  __bf16* wsq = qkv;
  __bf16* wsk = qkv + (size_t)M_ * D_;
  __bf16* wsv = qkv + (size_t)2 * M_ * D_;

  conv_x<<<(M_ * (D_ / 8)) / 256, 256, 0, stream>>>(x, xb);
  conv_w<<<dim3(D_ / 64, D_ / 64, 3), 256, 0, stream>>>(Wq, Wk, Wv, wt);
  qkv_gemm<<<dim3(D_ / 128, M_ / 128, 3), 256, 0, stream>>>(xb, wt, bq, bk, bv, qkv);
  attn<<<dim3(NT_ / 2, H_, B_), 256, 0, stream>>>(wsq, wsk, wsv, out);
}

// Round 4
// 198.853 us; speedup vs baseline: 1.1559x; 1.1559x over previous
//
#include <hip/hip_runtime.h>
#include <hip/hip_bf16.h>

#define B_ 2
#define S_ 2048
#define D_ 1024
#define H_ 16
#define DH 64
#define M_ (B_*S_)   // 4096
#define NT_ (S_/64)  // 32 q tiles per (b,h)

using bf16x8 = __attribute__((ext_vector_type(8))) __bf16;
using f32x4  = __attribute__((ext_vector_type(4))) float;

// swizzle key: varies with row bits 0..2 AND 3..5 (element units, flips the
// 16B-block index within a 64-elem group)
__device__ __forceinline__ int swz(int row) { return ((row ^ (row >> 3)) & 7) << 3; }

__device__ __forceinline__ void glds16(const __bf16* g, __bf16* l) {
#if __has_builtin(__builtin_amdgcn_global_load_lds)
  __builtin_amdgcn_global_load_lds(
      (const __attribute__((address_space(1))) unsigned int*)g,
      (__attribute__((address_space(3))) unsigned int*)l, 16, 0, 0);
#else
  *(bf16x8*)l = *(const bf16x8*)g;
#endif
}

// ---------- convert x fp32 -> bf16, pre-swizzled within 64-col k-groups ----
__global__ __launch_bounds__(256) void conv_x(const float* __restrict__ x,
                                              __bf16* __restrict__ xb) {
  int idx = blockIdx.x * 256 + threadIdx.x;
  int m = idx >> 7, k = (idx & 127) * 8;
  float4 a = *(const float4*)&x[(size_t)m * D_ + k];
  float4 b = *(const float4*)&x[(size_t)m * D_ + k + 4];
  bf16x8 o;
  o[0]=(__bf16)a.x; o[1]=(__bf16)a.y; o[2]=(__bf16)a.z; o[3]=(__bf16)a.w;
  o[4]=(__bf16)b.x; o[5]=(__bf16)b.y; o[6]=(__bf16)b.z; o[7]=(__bf16)b.w;
  *(bf16x8*)&xb[(size_t)m * D_ + (k & ~63) + ((k & 63) ^ swz(m))] = o;
}

// ---------- transpose+convert W [k][n] fp32 -> Wt [n][k] bf16 (pre-swz) ----
__global__ __launch_bounds__(256) void conv_w(const float* __restrict__ Wq,
                                              const float* __restrict__ Wk,
                                              const float* __restrict__ Wv,
                                              __bf16* __restrict__ wt) {
  int z = blockIdx.z;
  const float* __restrict__ W = (z == 0) ? Wq : (z == 1) ? Wk : Wv;
  __bf16* __restrict__ Wt = wt + (size_t)z * D_ * D_;
  __shared__ __bf16 Lt[64 * 66];
  int tid = threadIdx.x;
  int k0 = blockIdx.x * 64, n0 = blockIdx.y * 64;
  #pragma unroll
  for (int i = 0; i < 4; ++i) {
    int f4 = i * 256 + tid;
    int r = f4 >> 4, c4 = (f4 & 15) * 4;
    float4 v = *(const float4*)&W[(size_t)(k0 + r) * D_ + n0 + c4];
    Lt[(c4 + 0) * 66 + r] = (__bf16)v.x;
    Lt[(c4 + 1) * 66 + r] = (__bf16)v.y;
    Lt[(c4 + 2) * 66 + r] = (__bf16)v.z;
    Lt[(c4 + 3) * 66 + r] = (__bf16)v.w;
  }
  __syncthreads();
  #pragma unroll
  for (int i = 0; i < 2; ++i) {
    int idx = i * 256 + tid;
    int n = idx >> 3, kc = (idx & 7) * 8;
    int nf = n0 + n;
    bf16x8 o;
    #pragma unroll
    for (int j = 0; j < 8; ++j) o[j] = Lt[n * 66 + kc + j];
    *(bf16x8*)&Wt[(size_t)nf * D_ + k0 + (kc ^ swz(nf))] = o;
  }
}

// ---------- QKV GEMM: 256x256 tile, BK=64, 8 waves, 2-phase LDS dbuf -------
#define BM 256
#define BN 256
#define BK 64
#define NKT (D_/BK)  // 16

__global__ __launch_bounds__(512, 2) void qkv_gemm(
    const __bf16* __restrict__ xb, const __bf16* __restrict__ wt,
    const float* __restrict__ bq, const float* __restrict__ bk,
    const float* __restrict__ bv, __bf16* __restrict__ qkv) {
  int z = blockIdx.z;
  const __bf16* __restrict__ Wt = wt + (size_t)z * D_ * D_;
  const float* __restrict__ bias = (z == 0) ? bq : (z == 1) ? bk : bv;
  __bf16* __restrict__ out = qkv + (size_t)z * M_ * D_;
  const float scale = (z == 0) ? 0.125f : 1.0f;

  __shared__ __bf16 Al[2][BM * BK];  // 2 x 32KB
  __shared__ __bf16 Bl[2][BM * BK];  // 2 x 32KB  (B rows = n of W^T)

  int tid = threadIdx.x, lane = tid & 63, w = tid >> 6;  // 8 waves
  int m0 = blockIdx.y * BM, n0 = blockIdx.x * BN;
  int wr = (w >> 2) * 128;   // 2 M-groups of 128
  int wc = (w & 3) * 64;     // 4 N-groups of 64

  f32x4 acc[8][4] = {};

#define STAGE(buf, kt)                                                        \
  {                                                                           \
    int k0 = (kt) * BK;                                                       \
    _Pragma("unroll")                                                         \
    for (int r = 0; r < 4; ++r) {                                             \
      int e = (r * 512 + tid) * 8;                                            \
      int row = e >> 6, col = e & 63;                                         \
      glds16(&xb[(size_t)(m0 + row) * D_ + k0 + col], &Al[buf][e]);           \
      glds16(&Wt[(size_t)(n0 + row) * D_ + k0 + col], &Bl[buf][e]);           \
    }                                                                         \
  }

  STAGE(0, 0);
  __syncthreads();

  int cur = 0;
  for (int kt = 0; kt < NKT; ++kt) {
    if (kt + 1 < NKT) STAGE(cur ^ 1, kt + 1);   // loads fly under compute
    #pragma unroll
    for (int kk = 0; kk < 2; ++kk) {
      bf16x8 af[8], bfr[4];
      #pragma unroll
      for (int mi = 0; mi < 8; ++mi) {
        int row = wr + mi * 16 + (lane & 15);
        af[mi] = *(const bf16x8*)&Al[cur][row * 64 +
                 ((kk * 32 + (lane >> 4) * 8) ^ swz(row))];
      }
      #pragma unroll
      for (int ni = 0; ni < 4; ++ni) {
        int col = wc + ni * 16 + (lane & 15);
        bfr[ni] = *(const bf16x8*)&Bl[cur][col * 64 +
                  ((kk * 32 + (lane >> 4) * 8) ^ swz(col))];
      }
      #pragma unroll
      for (int mi = 0; mi < 8; ++mi)
        #pragma unroll
        for (int ni = 0; ni < 4; ++ni)
          acc[mi][ni] = __builtin_amdgcn_mfma_f32_16x16x32_bf16(
              af[mi], bfr[ni], acc[mi][ni], 0, 0, 0);
    }
    __syncthreads();   // drains stage (vmcnt) + read-done for buffer reuse
    cur ^= 1;
  }
#undef STAGE

  // epilogue: C/D layout col=lane&15, row=(lane>>4)*4+r; out [B][H][S][dh]
  #pragma unroll
  for (int mi = 0; mi < 8; ++mi) {
    #pragma unroll
    for (int ni = 0; ni < 4; ++ni) {
      int col = n0 + wc + ni * 16 + (lane & 15);
      int h = col >> 6, dh = col & 63;
      float bv_ = bias[col];
      #pragma unroll
      for (int r = 0; r < 4; ++r) {
        int row = m0 + wr + mi * 16 + (lane >> 4) * 4 + r;
        int b = row >> 11, s = row & 2047;
        out[((size_t)(b * H_ + h) * S_ + s) * DH + dh] =
            (__bf16)((acc[mi][ni][r] + bv_) * scale);
      }
    }
  }
}

// ---------- flash attention (R2 structure, KVB=64, paired q-tiles) ---------
__device__ __forceinline__ void attn_tile(
    const bf16x8* aq, f32x4* accO, float* mrow, float* lrow,
    const __bf16* __restrict__ Kl, const __bf16* __restrict__ Vt,
    __bf16* __restrict__ Plw, int lane, int kv0, int qbase, int diag) {
  f32x4 sf[4];
  __builtin_amdgcn_s_setprio(1);
  #pragma unroll
  for (int f = 0; f < 4; ++f) {
    f32x4 zz = {};
    int col = f * 16 + (lane & 15);
    int sc = swz(col);
    #pragma unroll
    for (int kk = 0; kk < 2; ++kk) {
      bf16x8 bk = *(const bf16x8*)&Kl[col * 64 + ((kk * 32 + (lane >> 4) * 8) ^ sc)];
      zz = __builtin_amdgcn_mfma_f32_16x16x32_bf16(aq[kk], bk, zz, 0, 0, 0);
    }
    sf[f] = zz;
  }
  __builtin_amdgcn_s_setprio(0);

  if (diag) {
    #pragma unroll
    for (int f = 0; f < 4; ++f) {
      int kvg = kv0 + f * 16 + (lane & 15);
      #pragma unroll
      for (int r = 0; r < 4; ++r) {
        int qg = qbase + (lane >> 4) * 4 + r;
        if (kvg > qg) sf[f][r] = -1e30f;
      }
    }
  }

  float alpha[4];
  #pragma unroll
  for (int r = 0; r < 4; ++r) {
    float mx = fmaxf(fmaxf(sf[0][r], sf[1][r]), fmaxf(sf[2][r], sf[3][r]));
    #pragma unroll
    for (int off = 8; off >= 1; off >>= 1)
      mx = fmaxf(mx, __shfl_xor(mx, off, 64));
    float mnew = fmaxf(mrow[r], mx);
    alpha[r] = __expf(mrow[r] - mnew);
    mrow[r] = mnew;
    float rs = 0.f;
    #pragma unroll
    for (int f = 0; f < 4; ++f) {
      float p = __expf(sf[f][r] - mnew);
      sf[f][r] = p;
      rs += p;
    }
    #pragma unroll
    for (int off = 8; off >= 1; off >>= 1)
      rs += __shfl_xor(rs, off, 64);
    lrow[r] = lrow[r] * alpha[r] + rs;
  }

  #pragma unroll
  for (int f = 0; f < 4; ++f)
    #pragma unroll
    for (int r = 0; r < 4; ++r) {
      int row = (lane >> 4) * 4 + r;
      Plw[row * 64 + ((f * 16 + (lane & 15)) ^ swz(row))] = (__bf16)sf[f][r];
    }

  #pragma unroll
  for (int f = 0; f < 4; ++f)
    #pragma unroll
    for (int r = 0; r < 4; ++r)
      accO[f][r] *= alpha[r];

  __builtin_amdgcn_s_setprio(1);
  #pragma unroll
  for (int kk = 0; kk < 2; ++kk) {
    int prow = lane & 15;
    bf16x8 pa = *(const bf16x8*)&Plw[prow * 64 + ((kk * 32 + (lane >> 4) * 8) ^ swz(prow))];
    #pragma unroll
    for (int f = 0; f < 4; ++f) {
      int vrow = f * 16 + (lane & 15);
      bf16x8 vb = *(const bf16x8*)&Vt[vrow * 64 + ((kk * 32 + (lane >> 4) * 8) ^ swz(vrow))];
      accO[f] = __builtin_amdgcn_mfma_f32_16x16x32_bf16(pa, vb, accO[f], 0, 0, 0);
    }
  }
  __builtin_amdgcn_s_setprio(0);
}

__device__ __forceinline__ void attn_out(
    const f32x4* accO, const float* lrow, float* __restrict__ out,
    int b, int h, int qbase, int lane) {
  #pragma unroll
  for (int f = 0; f < 4; ++f) {
    int dh = f * 16 + (lane & 15);
    #pragma unroll
    for (int r = 0; r < 4; ++r) {
      int qg = qbase + (lane >> 4) * 4 + r;
      out[((size_t)(b * S_ + qg)) * D_ + h * DH + dh] = accO[f][r] / lrow[r];
    }
  }
}

__global__ __launch_bounds__(256) void attn(
    const __bf16* __restrict__ Q, const __bf16* __restrict__ K,
    const __bf16* __restrict__ V, float* __restrict__ out) {
  __shared__ __bf16 Kl[64 * 64];     // [kv][dh], swizzled
  __shared__ __bf16 Vt[64 * 64];     // [dh][kv], swizzled
  __shared__ __bf16 Pl[4][16 * 64];  // per-wave P

  int tid = threadIdx.x, lane = tid & 63, w = tid >> 6;
  int bx = blockIdx.x, h = blockIdx.y, b = blockIdx.z;
  int qA0 = bx * 64, qB0 = (NT_ - 1 - bx) * 64;   // paired tiles: i and 31-i
  size_t base = ((size_t)(b * H_ + h)) * S_ * DH;
  const __bf16* __restrict__ Qg = Q + base;
  const __bf16* __restrict__ Kg = K + base;
  const __bf16* __restrict__ Vg = V + base;

  bf16x8 aqA[2], aqB[2];
  int qra = qA0 + w * 16 + (lane & 15), qrb = qB0 + w * 16 + (lane & 15);
  #pragma unroll
  for (int kk = 0; kk < 2; ++kk) {
    aqA[kk] = *(const bf16x8*)&Qg[(size_t)qra * DH + kk * 32 + (lane >> 4) * 8];
    aqB[kk] = *(const bf16x8*)&Qg[(size_t)qrb * DH + kk * 32 + (lane >> 4) * 8];
  }

  f32x4 accA[4] = {}, accB[4] = {};
  float mA[4], lA[4], mB[4], lB[4];
  #pragma unroll
  for (int r = 0; r < 4; ++r) { mA[r] = mB[r] = -1e30f; lA[r] = lB[r] = 0.f; }

  const int ktA = bx, ktB = NT_ - 1 - bx;
  for (int kt = 0; kt <= ktB; ++kt) {
    int kv0 = kt * 64;
    #pragma unroll
    for (int i = 0; i < 2; ++i) {
      int e = (i * 256 + tid) * 8;
      int kv = e >> 6, d0 = e & 63;
      bf16x8 k8 = *(const bf16x8*)&Kg[(size_t)(kv0 + kv) * DH + d0];
      *(bf16x8*)&Kl[kv * 64 + (d0 ^ swz(kv))] = k8;
      bf16x8 v8 = *(const bf16x8*)&Vg[(size_t)(kv0 + kv) * DH + d0];
      #pragma unroll
      for (int j = 0; j < 8; ++j) {
        int row = d0 + j;
        Vt[row * 64 + (kv ^ swz(row))] = v8[j];
      }
    }
    __syncthreads();

    attn_tile(aqB, accB, mB, lB, Kl, Vt, Pl[w], lane, kv0, qB0 + w * 16, kt == ktB);
    if (kt <= ktA)
      attn_tile(aqA, accA, mA, lA, Kl, Vt, Pl[w], lane, kv0, qA0 + w * 16, kt == ktA);
    __syncthreads();
  }

  attn_out(accA, lA, out, b, h, qA0 + w * 16, lane);
  attn_out(accB, lB, out, b, h, qB0 + w * 16, lane);
}

extern "C" void kernel_launch(void* const* d_in, const int* in_sizes, int n_in,
                              void* d_out, int out_size, void* d_ws, size_t ws_size,
                              hipStream_t stream) {
  const float* x  = (const float*)d_in[0];
  const float* Wq = (const float*)d_in[1];
  const float* bq = (const float*)d_in[2];
  const float* Wk = (const float*)d_in[3];
  const float* bk = (const float*)d_in[4];
  const float* Wv = (const float*)d_in[5];
  const float* bv = (const float*)d_in[6];
  float* out = (float*)d_out;

  __bf16* xb  = (__bf16*)d_ws;             // 8 MB
  __bf16* wt  = xb + (size_t)M_ * D_;      // 6 MB
  __bf16* qkv = wt + (size_t)3 * D_ * D_;  // 24 MB
  __bf16* wsq = qkv;
  __bf16* wsk = qkv + (size_t)M_ * D_;
  __bf16* wsv = qkv + (size_t)2 * M_ * D_;

  conv_x<<<(M_ * (D_ / 8)) / 256, 256, 0, stream>>>(x, xb);
  conv_w<<<dim3(D_ / 64, D_ / 64, 3), 256, 0, stream>>>(Wq, Wk, Wv, wt);
  qkv_gemm<<<dim3(D_ / BN, M_ / BM, 3), 512, 0, stream>>>(xb, wt, bq, bk, bv, qkv);
  attn<<<dim3(NT_ / 2, H_, B_), 256, 0, stream>>>(wsq, wsk, wsv, out);
}